// Round 1
// baseline (518.525 us; speedup 1.0000x reference)
//
#include <hip/hip_runtime.h>

// ---- problem dims ----
#define IN_DIM 8193
#define OUT_DIM 4097
#define NB 1024
// padded dims (M -> mult of 128, K -> mult of 64)
#define MP1 8320
#define KP1 8256
#define MP2 4224
#define KP2 4160

typedef __attribute__((ext_vector_type(8))) short short8;
typedef __attribute__((ext_vector_type(4))) float f32x4;

__device__ __forceinline__ unsigned short f2bf(float f) {
  unsigned int u = __float_as_uint(f);
  u = (u + 0x7fffu + ((u >> 16) & 1u)) >> 16;  // RNE
  return (unsigned short)u;
}

// ---- pad + f32->bf16 convert (row-major -> row-major padded) ----
__global__ __launch_bounds__(256) void cvt_pad_kernel(
    const float* __restrict__ src, unsigned short* __restrict__ dst,
    int sR, int sC, int dR, int dC) {
  int gid = blockIdx.x * 256 + threadIdx.x;
  int i4 = gid * 4;
  if (i4 >= dR * dC) return;
  int r = i4 / dC;
  int c = i4 - r * dC;   // dC % 4 == 0 so never crosses a row
  unsigned short o[4];
#pragma unroll
  for (int j = 0; j < 4; ++j) {
    int cc = c + j;
    float v = (r < sR && cc < sC) ? src[(size_t)r * sC + cc] : 0.f;
    o[j] = f2bf(v);
  }
  unsigned int lo = (unsigned)o[0] | ((unsigned)o[1] << 16);
  unsigned int hi = (unsigned)o[2] | ((unsigned)o[3] << 16);
  *reinterpret_cast<uint2*>(dst + i4) = make_uint2(lo, hi);
}

// ---- transpose + convert: src (K x N) f32 -> dst (N x Kp) bf16, zero pad k>=K ----
__global__ __launch_bounds__(256) void transpose_cvt_kernel(
    const float* __restrict__ src, unsigned short* __restrict__ dst,
    int K, int N, int Kp) {
  __shared__ float tl[32][33];
  const int ntk = Kp >> 5;
  int bx = blockIdx.x % ntk;
  int by = blockIdx.x / ntk;
  int k0 = bx * 32, n0 = by * 32;
  int tx = threadIdx.x & 31, ty = threadIdx.x >> 5;
#pragma unroll
  for (int i = 0; i < 4; ++i) {
    int k = k0 + ty + i * 8;
    tl[ty + i * 8][tx] = (k < K) ? src[(size_t)k * N + n0 + tx] : 0.f;
  }
  __syncthreads();
#pragma unroll
  for (int i = 0; i < 4; ++i) {
    int n = n0 + ty + i * 8;
    dst[(size_t)n * Kp + k0 + tx] = f2bf(tl[tx][ty + i * 8]);
  }
}

// ---- GEMM: C(Mout x N) = Ab(Mp x Kp) * Bt(N x Kp)^T, bf16 in / f32 out ----
// 128x128 tile, BK=64, 4 waves (2x2), 16x16x32 MFMA, global_load_lds staging
// with XOR granule swizzle (g ^= row&7) on both source addr and ds_read.
__global__ __launch_bounds__(256) void gemm_bt(
    const unsigned short* __restrict__ Ab,
    const unsigned short* __restrict__ Bt,
    float* __restrict__ C,
    int Kp, int Mout, int N) {
  __shared__ unsigned short As[128 * 64];
  __shared__ unsigned short Bs[128 * 64];
  const int tid = threadIdx.x;
  const int wid = tid >> 6;
  const int lane = tid & 63;
  const int nbn = N >> 7;
  const int bm = blockIdx.x / nbn;
  const int bn = blockIdx.x - bm * nbn;
  const int m0 = bm << 7, n0 = bn << 7;
  const int wm = (wid >> 1) << 6;  // 0 or 64
  const int wn = (wid & 1) << 6;   // 0 or 64

  f32x4 acc[4][4] = {};

  const int nk = Kp >> 6;
  for (int kt = 0; kt < nk; ++kt) {
    const int k0 = kt << 6;
    // stage A,B tiles: 1024 16B-slots each; slot s -> (row=s>>3, phys granule s&7)
    // physical slot holds logical granule (s&7)^(row&7)  (inverse-swizzled source)
#pragma unroll
    for (int i = 0; i < 4; ++i) {
      const int s = i * 256 + tid;
      const int row = s >> 3;
      const int gl = (s & 7) ^ (row & 7);
      const unsigned short* ga = Ab + (size_t)(m0 + row) * Kp + (k0 + gl * 8);
      const unsigned short* gb = Bt + (size_t)(n0 + row) * Kp + (k0 + gl * 8);
      unsigned short* la = As + (size_t)(i * 256 + wid * 64) * 8;  // wave-uniform base
      unsigned short* lb = Bs + (size_t)(i * 256 + wid * 64) * 8;
      __builtin_amdgcn_global_load_lds(
          (const __attribute__((address_space(1))) void*)ga,
          (__attribute__((address_space(3))) void*)la, 16, 0, 0);
      __builtin_amdgcn_global_load_lds(
          (const __attribute__((address_space(1))) void*)gb,
          (__attribute__((address_space(3))) void*)lb, 16, 0, 0);
    }
    __syncthreads();
#pragma unroll
    for (int kk = 0; kk < 2; ++kk) {
      short8 af[4], bfr[4];
#pragma unroll
      for (int mf = 0; mf < 4; ++mf) {
        const int row = wm + mf * 16 + (lane & 15);
        const int g = (kk * 4 + (lane >> 4)) ^ (row & 7);
        af[mf] = *reinterpret_cast<const short8*>(As + row * 64 + g * 8);
      }
#pragma unroll
      for (int nf = 0; nf < 4; ++nf) {
        const int row = wn + nf * 16 + (lane & 15);
        const int g = (kk * 4 + (lane >> 4)) ^ (row & 7);
        bfr[nf] = *reinterpret_cast<const short8*>(Bs + row * 64 + g * 8);
      }
#pragma unroll
      for (int mf = 0; mf < 4; ++mf)
#pragma unroll
        for (int nf = 0; nf < 4; ++nf)
          asm volatile("v_mfma_f32_16x16x32_bf16 %0, %1, %2, %0"
                       : "+v"(acc[mf][nf])
                       : "v"(af[mf]), "v"(bfr[nf]));
    }
    __syncthreads();
  }
  // epilogue: C/D layout col=lane&15, row=(lane>>4)*4+reg  [m89-verified]
#pragma unroll
  for (int mf = 0; mf < 4; ++mf) {
    const int rbase = m0 + wm + mf * 16 + (lane >> 4) * 4;
#pragma unroll
    for (int nf = 0; nf < 4; ++nf) {
      const int col = n0 + wn + nf * 16 + (lane & 15);
#pragma unroll
      for (int r = 0; r < 4; ++r) {
        const int row = rbase + r;
        if (row < Mout) C[(size_t)row * N + col] = acc[mf][nf][r];
      }
    }
  }
}

// ---- conv: z (8193 x 1024) f32 -> tT (1024 x KP2) bf16 (transposed t) ----
// t[r,n], r = co*256 + uo*16 + vo ; stride 2, SAME (pad_lo=0), K=3
// row 4096 = hom ; rows 4097..4159 = 0
__global__ __launch_bounds__(256) void conv_tT_kernel(
    const float* __restrict__ z, const float* __restrict__ w,
    const float* __restrict__ bias, unsigned short* __restrict__ tT) {
  const int gid = blockIdx.x * 256 + threadIdx.x;
  const int n = gid & 1023;
  const int rg = gid >> 10;  // 0..519
  const int r0 = rg << 3;
  const float hom = z[(size_t)8192 * 1024 + n];
  unsigned short o[8];
  if (r0 >= 4096) {
#pragma unroll
    for (int j = 0; j < 8; ++j) o[j] = f2bf((r0 + j == 4096) ? hom : 0.f);
  } else {
    const int co = r0 >> 8;
    const int uo = (r0 >> 4) & 15;
    const int vo0 = r0 & 15;  // 0 or 8
    float acc[8];
    const float bb = bias[co];
#pragma unroll
    for (int j = 0; j < 8; ++j) acc[j] = bb * hom;
    for (int ci = 0; ci < 8; ++ci) {
#pragma unroll
      for (int kh = 0; kh < 3; ++kh) {
        const int u = uo * 2 + kh;
        if (u >= 32) continue;
        const float* zbase = z + (size_t)(ci * 1024 + u * 32) * 1024 + n;
#pragma unroll
        for (int kw = 0; kw < 3; ++kw) {
          const float wv = w[((co * 8 + ci) * 3 + kh) * 3 + kw];
#pragma unroll
          for (int j = 0; j < 8; ++j) {
            const int v = (vo0 + j) * 2 + kw;
            if (v < 32) acc[j] += wv * zbase[(size_t)v * 1024];
          }
        }
      }
    }
#pragma unroll
    for (int j = 0; j < 8; ++j) o[j] = f2bf(acc[j]);
  }
  uint4 pv;
  pv.x = (unsigned)o[0] | ((unsigned)o[1] << 16);
  pv.y = (unsigned)o[2] | ((unsigned)o[3] << 16);
  pv.z = (unsigned)o[4] | ((unsigned)o[5] << 16);
  pv.w = (unsigned)o[6] | ((unsigned)o[7] << 16);
  *reinterpret_cast<uint4*>(tT + (size_t)n * KP2 + r0) = pv;
}

extern "C" void kernel_launch(void* const* d_in, const int* in_sizes, int n_in,
                              void* d_out, int out_size, void* d_ws, size_t ws_size,
                              hipStream_t stream) {
  const float* w    = (const float*)d_in[0];  // (16,8,3,3)
  const float* bias = (const float*)d_in[1];  // (16,)
  const float* A    = (const float*)d_in[2];  // (4097,4097)
  const float* Ainv = (const float*)d_in[3];  // (8193,8193)
  const float* x    = (const float*)d_in[4];  // (8193,1024)
  float* out = (float*)d_out;                 // (4097,1024)

  char* ws = (char*)d_ws;
  size_t off = 0;
  unsigned short* Ainv_b = (unsigned short*)(ws + off); off += (size_t)MP1 * KP1 * 2;  // 137.4 MB
  unsigned short* xT_b   = (unsigned short*)(ws + off); off += (size_t)NB * KP1 * 2;   // 16.9 MB
  float*          z      = (float*)(ws + off);          off += (size_t)IN_DIM * NB * 4; // 33.6 MB
  unsigned short* A2_b   = (unsigned short*)(ws + off); off += (size_t)MP2 * KP2 * 2;  // 35.1 MB
  unsigned short* tT_b   = (unsigned short*)(ws + off); off += (size_t)NB * KP2 * 2;   // 8.5 MB
  (void)ws_size; (void)in_sizes; (void)n_in; (void)out_size;

  // 1) Ainv -> padded bf16 (MP1 x KP1)
  cvt_pad_kernel<<<(MP1 * KP1 / 4 + 255) / 256, 256, 0, stream>>>(
      Ainv, Ainv_b, IN_DIM, IN_DIM, MP1, KP1);
  // 2) x -> x^T padded bf16 (NB x KP1)
  transpose_cvt_kernel<<<(KP1 / 32) * (NB / 32), 256, 0, stream>>>(
      x, xT_b, IN_DIM, NB, KP1);
  // 3) A -> padded bf16 (MP2 x KP2)
  cvt_pad_kernel<<<(MP2 * KP2 / 4 + 255) / 256, 256, 0, stream>>>(
      A, A2_b, OUT_DIM, OUT_DIM, MP2, KP2);
  // 4) z = Ainv @ x
  gemm_bt<<<(MP1 / 128) * (NB / 128), 256, 0, stream>>>(
      Ainv_b, xT_b, z, KP1, IN_DIM, NB);
  // 5) t^T = conv(z)  (incl. hom row + zero pad)
  conv_tT_kernel<<<(520 * 1024) / 256, 256, 0, stream>>>(z, w, bias, tT_b);
  // 6) out = A @ t
  gemm_bt<<<(MP2 / 128) * (NB / 128), 256, 0, stream>>>(
      A2_b, tT_b, out, KP2, OUT_DIM, NB);
}

// Round 2
// 440.452 us; speedup vs baseline: 1.1773x; 1.1773x over previous
//
#include <hip/hip_runtime.h>

// ---- problem dims ----
#define IN_DIM 8193
#define OUT_DIM 4097
#define NB 1024
// padded dims (M -> mult of 128, K -> mult of 64)
#define MP1 8320
#define KP1 8256
#define MP2 4224
#define KP2 4160

typedef __attribute__((ext_vector_type(8))) short short8;
typedef __attribute__((ext_vector_type(4))) float f32x4;

__device__ __forceinline__ unsigned short f2bf(float f) {
  unsigned int u = __float_as_uint(f);
  u = (u + 0x7fffu + ((u >> 16) & 1u)) >> 16;  // RNE
  return (unsigned short)u;
}

// ---- pad + f32->bf16 convert (row-major -> row-major padded) ----
__global__ __launch_bounds__(256) void cvt_pad_kernel(
    const float* __restrict__ src, unsigned short* __restrict__ dst,
    int sR, int sC, int dR, int dC) {
  int gid = blockIdx.x * 256 + threadIdx.x;
  int i4 = gid * 4;
  if (i4 >= dR * dC) return;
  int r = i4 / dC;
  int c = i4 - r * dC;   // dC % 4 == 0 so never crosses a row
  unsigned short o[4];
#pragma unroll
  for (int j = 0; j < 4; ++j) {
    int cc = c + j;
    float v = (r < sR && cc < sC) ? src[(size_t)r * sC + cc] : 0.f;
    o[j] = f2bf(v);
  }
  unsigned int lo = (unsigned)o[0] | ((unsigned)o[1] << 16);
  unsigned int hi = (unsigned)o[2] | ((unsigned)o[3] << 16);
  *reinterpret_cast<uint2*>(dst + i4) = make_uint2(lo, hi);
}

// ---- transpose + convert: src (K x N) f32 -> dst (N x Kp) bf16, zero pad k>=K ----
__global__ __launch_bounds__(256) void transpose_cvt_kernel(
    const float* __restrict__ src, unsigned short* __restrict__ dst,
    int K, int N, int Kp) {
  __shared__ float tl[32][33];
  const int ntk = Kp >> 5;
  int bx = blockIdx.x % ntk;
  int by = blockIdx.x / ntk;
  int k0 = bx * 32, n0 = by * 32;
  int tx = threadIdx.x & 31, ty = threadIdx.x >> 5;
#pragma unroll
  for (int i = 0; i < 4; ++i) {
    int k = k0 + ty + i * 8;
    tl[ty + i * 8][tx] = (k < K) ? src[(size_t)k * N + n0 + tx] : 0.f;
  }
  __syncthreads();
#pragma unroll
  for (int i = 0; i < 4; ++i) {
    int n = n0 + ty + i * 8;
    dst[(size_t)n * Kp + k0 + tx] = f2bf(tl[tx][ty + i * 8]);
  }
}

// ---- GEMM: C(Mout x N) = Ab(Mp x Kp) * Bt(N x Kp)^T, bf16 in / f32 out ----
// 128x128 tile, BK=64, 8 waves (2Mx4N, each wave 64x32), 16x16x32 MFMA,
// global_load_lds staging with XOR granule swizzle (g ^= row&7).
// XCD-aware block remap: all 8 N-blocks of one A-panel -> same XCD L2.
__global__ __launch_bounds__(512, 4) void gemm_bt(
    const unsigned short* __restrict__ Ab,
    const unsigned short* __restrict__ Bt,
    float* __restrict__ C,
    int Kp, int Mout, int N) {
  __shared__ unsigned short As[128 * 64];
  __shared__ unsigned short Bs[128 * 64];
  const int tid = threadIdx.x;
  const int wid = tid >> 6;
  const int lane = tid & 63;
  // XCD-aware bijective remap (nbn == 8 always here; default XCD = i%8)
  const int nbm = gridDim.x >> 3;
  const int full = (nbm & ~7) << 3;
  int bm, bn;
  {
    const int i = blockIdx.x;
    if (i < full) {
      bm = ((i >> 6) << 3) + (i & 7);
      bn = (i >> 3) & 7;
    } else {
      const int r = i - full;
      bm = (full >> 3) + (r >> 3);
      bn = r & 7;
    }
  }
  const int m0 = bm << 7, n0 = bn << 7;
  const int wm = (wid >> 2) << 6;   // 0 or 64
  const int wn = (wid & 3) << 5;    // 0,32,64,96

  f32x4 acc[4][2] = {};

  const int nk = Kp >> 6;
  for (int kt = 0; kt < nk; ++kt) {
    const int k0 = kt << 6;
    // stage A,B tiles: 1024 16B-slots each; slot s -> (row=s>>3, phys granule s&7)
    // physical slot holds logical granule (s&7)^(row&7)  (inverse-swizzled source)
#pragma unroll
    for (int i = 0; i < 2; ++i) {
      const int s = i * 512 + tid;
      const int row = s >> 3;
      const int gl = (s & 7) ^ (row & 7);
      const unsigned short* ga = Ab + (size_t)(m0 + row) * Kp + (k0 + gl * 8);
      const unsigned short* gb = Bt + (size_t)(n0 + row) * Kp + (k0 + gl * 8);
      unsigned short* la = As + (size_t)(i * 512 + wid * 64) * 8;  // wave-uniform base
      unsigned short* lb = Bs + (size_t)(i * 512 + wid * 64) * 8;
      __builtin_amdgcn_global_load_lds(
          (const __attribute__((address_space(1))) void*)ga,
          (__attribute__((address_space(3))) void*)la, 16, 0, 0);
      __builtin_amdgcn_global_load_lds(
          (const __attribute__((address_space(1))) void*)gb,
          (__attribute__((address_space(3))) void*)lb, 16, 0, 0);
    }
    __syncthreads();
#pragma unroll
    for (int kk = 0; kk < 2; ++kk) {
      short8 af[4], bfr[2];
#pragma unroll
      for (int mf = 0; mf < 4; ++mf) {
        const int row = wm + mf * 16 + (lane & 15);
        const int g = (kk * 4 + (lane >> 4)) ^ (row & 7);
        af[mf] = *reinterpret_cast<const short8*>(As + row * 64 + g * 8);
      }
#pragma unroll
      for (int nf = 0; nf < 2; ++nf) {
        const int row = wn + nf * 16 + (lane & 15);
        const int g = (kk * 4 + (lane >> 4)) ^ (row & 7);
        bfr[nf] = *reinterpret_cast<const short8*>(Bs + row * 64 + g * 8);
      }
#pragma unroll
      for (int mf = 0; mf < 4; ++mf)
#pragma unroll
        for (int nf = 0; nf < 2; ++nf)
          asm volatile("v_mfma_f32_16x16x32_bf16 %0, %1, %2, %0"
                       : "+v"(acc[mf][nf])
                       : "v"(af[mf]), "v"(bfr[nf]));
    }
    __syncthreads();
  }
  // epilogue: C/D layout col=lane&15, row=(lane>>4)*4+reg  [m89-verified]
#pragma unroll
  for (int mf = 0; mf < 4; ++mf) {
    const int rbase = m0 + wm + mf * 16 + (lane >> 4) * 4;
#pragma unroll
    for (int nf = 0; nf < 2; ++nf) {
      const int col = n0 + wn + nf * 16 + (lane & 15);
#pragma unroll
      for (int r = 0; r < 4; ++r) {
        const int row = rbase + r;
        if (row < Mout) C[(size_t)row * N + col] = acc[mf][nf][r];
      }
    }
  }
}

// ---- conv: z (8193 x 1024) f32 -> tT (1024 x KP2) bf16 (transposed t) ----
// t[r,n], r = co*256 + uo*16 + vo ; stride 2, SAME (pad_lo=0), K=3
// row 4096 = hom ; rows 4097..4159 = 0
__global__ __launch_bounds__(256) void conv_tT_kernel(
    const float* __restrict__ z, const float* __restrict__ w,
    const float* __restrict__ bias, unsigned short* __restrict__ tT) {
  const int gid = blockIdx.x * 256 + threadIdx.x;
  const int n = gid & 1023;
  const int rg = gid >> 10;  // 0..519
  const int r0 = rg << 3;
  const float hom = z[(size_t)8192 * 1024 + n];
  unsigned short o[8];
  if (r0 >= 4096) {
#pragma unroll
    for (int j = 0; j < 8; ++j) o[j] = f2bf((r0 + j == 4096) ? hom : 0.f);
  } else {
    const int co = r0 >> 8;
    const int uo = (r0 >> 4) & 15;
    const int vo0 = r0 & 15;  // 0 or 8
    float acc[8];
    const float bb = bias[co];
#pragma unroll
    for (int j = 0; j < 8; ++j) acc[j] = bb * hom;
    for (int ci = 0; ci < 8; ++ci) {
#pragma unroll
      for (int kh = 0; kh < 3; ++kh) {
        const int u = uo * 2 + kh;
        if (u >= 32) continue;
        const float* zbase = z + (size_t)(ci * 1024 + u * 32) * 1024 + n;
#pragma unroll
        for (int kw = 0; kw < 3; ++kw) {
          const float wv = w[((co * 8 + ci) * 3 + kh) * 3 + kw];
#pragma unroll
          for (int j = 0; j < 8; ++j) {
            const int v = (vo0 + j) * 2 + kw;
            if (v < 32) acc[j] += wv * zbase[(size_t)v * 1024];
          }
        }
      }
    }
#pragma unroll
    for (int j = 0; j < 8; ++j) o[j] = f2bf(acc[j]);
  }
  uint4 pv;
  pv.x = (unsigned)o[0] | ((unsigned)o[1] << 16);
  pv.y = (unsigned)o[2] | ((unsigned)o[3] << 16);
  pv.z = (unsigned)o[4] | ((unsigned)o[5] << 16);
  pv.w = (unsigned)o[6] | ((unsigned)o[7] << 16);
  *reinterpret_cast<uint4*>(tT + (size_t)n * KP2 + r0) = pv;
}

extern "C" void kernel_launch(void* const* d_in, const int* in_sizes, int n_in,
                              void* d_out, int out_size, void* d_ws, size_t ws_size,
                              hipStream_t stream) {
  const float* w    = (const float*)d_in[0];  // (16,8,3,3)
  const float* bias = (const float*)d_in[1];  // (16,)
  const float* A    = (const float*)d_in[2];  // (4097,4097)
  const float* Ainv = (const float*)d_in[3];  // (8193,8193)
  const float* x    = (const float*)d_in[4];  // (8193,1024)
  float* out = (float*)d_out;                 // (4097,1024)

  char* ws = (char*)d_ws;
  size_t off = 0;
  unsigned short* Ainv_b = (unsigned short*)(ws + off); off += (size_t)MP1 * KP1 * 2;  // 137.4 MB
  unsigned short* xT_b   = (unsigned short*)(ws + off); off += (size_t)NB * KP1 * 2;   // 16.9 MB
  float*          z      = (float*)(ws + off);          off += (size_t)IN_DIM * NB * 4; // 33.6 MB
  unsigned short* A2_b   = (unsigned short*)(ws + off); off += (size_t)MP2 * KP2 * 2;  // 35.1 MB
  unsigned short* tT_b   = (unsigned short*)(ws + off); off += (size_t)NB * KP2 * 2;   // 8.5 MB
  (void)ws_size; (void)in_sizes; (void)n_in; (void)out_size;

  // 1) Ainv -> padded bf16 (MP1 x KP1)
  cvt_pad_kernel<<<(MP1 * KP1 / 4 + 255) / 256, 256, 0, stream>>>(
      Ainv, Ainv_b, IN_DIM, IN_DIM, MP1, KP1);
  // 2) x -> x^T padded bf16 (NB x KP1)
  transpose_cvt_kernel<<<(KP1 / 32) * (NB / 32), 256, 0, stream>>>(
      x, xT_b, IN_DIM, NB, KP1);
  // 3) A -> padded bf16 (MP2 x KP2)
  cvt_pad_kernel<<<(MP2 * KP2 / 4 + 255) / 256, 256, 0, stream>>>(
      A, A2_b, OUT_DIM, OUT_DIM, MP2, KP2);
  // 4) z = Ainv @ x
  gemm_bt<<<(MP1 / 128) * (NB / 128), 512, 0, stream>>>(
      Ainv_b, xT_b, z, KP1, IN_DIM, NB);
  // 5) t^T = conv(z)  (incl. hom row + zero pad)
  conv_tT_kernel<<<(520 * 1024) / 256, 256, 0, stream>>>(z, w, bias, tT_b);
  // 6) out = A @ t
  gemm_bt<<<(MP2 / 128) * (NB / 128), 512, 0, stream>>>(
      A2_b, tT_b, out, KP2, OUT_DIM, NB);
}